// Round 6
// baseline (118.609 us; speedup 1.0000x reference)
//
#include <hip/hip_runtime.h>

typedef short v8s __attribute__((ext_vector_type(8)));
typedef float v4f __attribute__((ext_vector_type(4)));

#define AS1 __attribute__((address_space(1)))
#define AS3 __attribute__((address_space(3)))

__device__ __forceinline__ ushort f2bf(float f) {
  union { float f; unsigned u; } v; v.f = f;
  unsigned u = v.u;
  unsigned r = (u + 0x7FFFu + ((u >> 16) & 1u)) >> 16;
  return (ushort)r;
}

__device__ __forceinline__ ushort f2bf_trunc(float f) {
  union { float f; unsigned u; } v; v.f = f;
  return (ushort)(v.u >> 16);
}

// ---------------- cast fp32 -> bf16 ----------------
__global__ void cast_bf16_kernel(const float* __restrict__ src, ushort* __restrict__ dst, int n4) {
  int i = blockIdx.x * blockDim.x + threadIdx.x;
  if (i < n4) {
    float4 f = ((const float4*)src)[i];
    ushort4 o;
    o.x = f2bf(f.x); o.y = f2bf(f.y); o.z = f2bf(f.z); o.w = f2bf(f.w);
    ((ushort4*)dst)[i] = o;
  }
}

// ---------------- QKV GEMM, 8-phase 256x256 (T2+T3+T4+T5) ----------------
// C[M=4096][N=3072] = A[M][K=1024] * B[N][K]^T, epilogue scatters q/k/v heads.
// 512 thr = 8 waves (2M x 4N), per-wave 128x64 out = 8x4 16x16 frags.
// LDS 128 KiB: 2 dbuf x (256x64 A + 256x64 B) bf16. K-tile = 64.
// Stage: global_load_lds w=16, linear dest, pre-swizzled source col
// ((l&7)^(l>>3))*8; reads XOR (lr&7)<<3 -> ~2-way conflicts (rule #21).
// Schedule per K-tile: P1{stage8(t+1) + ds A(m0-3),B(n0-1); bar; 16 MFMA; bar}
// P2{ds B(n2-3); bar; 16 MFMA; bar} P3{ds A(m4-7); bar; 16 MFMA; bar}
// P4{vmcnt(0) [t+1 landed, issued 3 phases ago]; bar; 16 MFMA; bar}.
// asm s_barrier with memory clobber = compiler fence for ds/stage ordering.
__global__ __launch_bounds__(512, 2)
void gemm_qkv_8ph(const ushort* __restrict__ A, const ushort* __restrict__ B,
                  ushort* __restrict__ q, ushort* __restrict__ k, ushort* __restrict__ v)
{
  constexpr int K = 1024;
  constexpr int NT = K / 64;
  __shared__ ushort lA[2][256 * 64];
  __shared__ ushort lB[2][256 * 64];
  const int tid = threadIdx.x;
  const int w = tid >> 6, lane = tid & 63;
  const int g = lane >> 4, lr = lane & 15;
  const int wm = w >> 2, wn = w & 3;
  const int m0 = blockIdx.x * 256, n0 = blockIdx.y * 256;

  const int r8 = lane >> 3;
  const int swz8 = ((lane & 7) ^ r8) * 8;   // pre-swizzled source col (ushort)
  const ushort* gA = A + (size_t)(m0 + w * 8 + r8) * K + swz8;
  const ushort* gB = B + (size_t)(n0 + w * 8 + r8) * K + swz8;

  v4f acc[8][4];
  const v4f zf = {0.0f, 0.0f, 0.0f, 0.0f};
#pragma unroll
  for (int m = 0; m < 8; m++)
#pragma unroll
    for (int n = 0; n < 4; n++) acc[m][n] = zf;

  auto stage8 = [&](int buf, int k0) {
#pragma unroll
    for (int j = 0; j < 4; j++) {
      __builtin_amdgcn_global_load_lds((const AS1 void*)(gA + (size_t)(j * 64) * K + k0),
                                       (AS3 void*)(&lA[buf][(j * 64 + w * 8) * 64]), 16, 0, 0);
      __builtin_amdgcn_global_load_lds((const AS1 void*)(gB + (size_t)(j * 64) * K + k0),
                                       (AS3 void*)(&lB[buf][(j * 64 + w * 8) * 64]), 16, 0, 0);
    }
  };

  stage8(0, 0);
  asm volatile("s_waitcnt vmcnt(0)" ::: "memory");
  asm volatile("s_barrier" ::: "memory");

  const int xr = (lr & 7) << 3;

  for (int t = 0; t < NT; t++) {
    const int bsel = t & 1;
    const ushort* cA = lA[bsel];
    const ushort* cB = lB[bsel];
    v8s a0[4][2], a1[4][2], b0[2][2], b1[2][2];

    // ---- P1: issue next-tile stages; read A(m0-3), B(n0-1); MFMA Q0
    if (t + 1 < NT) stage8(bsel ^ 1, (t + 1) * 64);
#pragma unroll
    for (int m = 0; m < 4; m++)
#pragma unroll
      for (int kc = 0; kc < 2; kc++)
        a0[m][kc] = *(const v8s*)(cA + (wm * 128 + m * 16 + lr) * 64 + ((kc * 32 + g * 8) ^ xr));
#pragma unroll
    for (int n = 0; n < 2; n++)
#pragma unroll
      for (int kc = 0; kc < 2; kc++)
        b0[n][kc] = *(const v8s*)(cB + (wn * 64 + n * 16 + lr) * 64 + ((kc * 32 + g * 8) ^ xr));
    asm volatile("s_barrier" ::: "memory");
    __builtin_amdgcn_s_setprio(1);
#pragma unroll
    for (int m = 0; m < 4; m++)
#pragma unroll
      for (int n = 0; n < 2; n++)
#pragma unroll
        for (int kc = 0; kc < 2; kc++)
          acc[m][n] = __builtin_amdgcn_mfma_f32_16x16x32_bf16(a0[m][kc], b0[n][kc], acc[m][n], 0, 0, 0);
    __builtin_amdgcn_s_setprio(0);
    asm volatile("s_barrier" ::: "memory");

    // ---- P2: read B(n2-3); MFMA Q1
#pragma unroll
    for (int n = 0; n < 2; n++)
#pragma unroll
      for (int kc = 0; kc < 2; kc++)
        b1[n][kc] = *(const v8s*)(cB + (wn * 64 + (n + 2) * 16 + lr) * 64 + ((kc * 32 + g * 8) ^ xr));
    asm volatile("s_barrier" ::: "memory");
    __builtin_amdgcn_s_setprio(1);
#pragma unroll
    for (int m = 0; m < 4; m++)
#pragma unroll
      for (int n = 0; n < 2; n++)
#pragma unroll
        for (int kc = 0; kc < 2; kc++)
          acc[m][n + 2] = __builtin_amdgcn_mfma_f32_16x16x32_bf16(a0[m][kc], b1[n][kc], acc[m][n + 2], 0, 0, 0);
    __builtin_amdgcn_s_setprio(0);
    asm volatile("s_barrier" ::: "memory");

    // ---- P3: read A(m4-7); MFMA Q2
#pragma unroll
    for (int m = 0; m < 4; m++)
#pragma unroll
      for (int kc = 0; kc < 2; kc++)
        a1[m][kc] = *(const v8s*)(cA + (wm * 128 + (m + 4) * 16 + lr) * 64 + ((kc * 32 + g * 8) ^ xr));
    asm volatile("s_barrier" ::: "memory");
    __builtin_amdgcn_s_setprio(1);
#pragma unroll
    for (int m = 0; m < 4; m++)
#pragma unroll
      for (int n = 0; n < 2; n++)
#pragma unroll
        for (int kc = 0; kc < 2; kc++)
          acc[m + 4][n] = __builtin_amdgcn_mfma_f32_16x16x32_bf16(a1[m][kc], b0[n][kc], acc[m + 4][n], 0, 0, 0);
    __builtin_amdgcn_s_setprio(0);
    asm volatile("s_barrier" ::: "memory");

    // ---- P4: drain next-tile stages (issued 3 phases ago); MFMA Q3
    if (t + 1 < NT) { asm volatile("s_waitcnt vmcnt(0)" ::: "memory"); }
    asm volatile("s_barrier" ::: "memory");
    __builtin_amdgcn_s_setprio(1);
#pragma unroll
    for (int m = 0; m < 4; m++)
#pragma unroll
      for (int n = 0; n < 2; n++)
#pragma unroll
        for (int kc = 0; kc < 2; kc++)
          acc[m + 4][n + 2] = __builtin_amdgcn_mfma_f32_16x16x32_bf16(a1[m][kc], b1[n][kc], acc[m + 4][n + 2], 0, 0, 0);
    __builtin_amdgcn_s_setprio(0);
    asm volatile("s_barrier" ::: "memory");
  }

  // epilogue: scatter into q/k/v head layout [B*nh][S][hd], Q scaled 0.125
#pragma unroll
  for (int m = 0; m < 8; m++) {
#pragma unroll
    for (int n = 0; n < 4; n++) {
      v4f c = acc[m][n];
      const int row0 = m0 + wm * 128 + m * 16 + g * 4;
      const int col = n0 + wn * 64 + n * 16 + lr;
#pragma unroll
      for (int r = 0; r < 4; r++) {
        const int mm = row0 + r;
        const int b = mm >> 11, s = mm & 2047;
        const int part = col >> 10, c2 = col & 1023;
        const int h = c2 >> 6, d = c2 & 63;
        const size_t idx = ((size_t)(b * 16 + h) * 2048 + s) * 64 + d;
        const float val = c[r];
        if (part == 0)      q[idx] = f2bf(val * 0.125f);
        else if (part == 1) k[idx] = f2bf(val);
        else                v[idx] = f2bf(val);
      }
    }
  }
}

// ---------------- GEMM: C[M][N] = A[M][K] * B[N][K]^T (bf16 in, fp32 acc) ----
// BM=128 fixed; BN in {128, 64}. 4 waves.
template<int MODE, int BN>
__global__ __launch_bounds__(256, 2)
void gemm_bt(const ushort* __restrict__ A, const ushort* __restrict__ B,
             ushort* __restrict__ q, ushort* __restrict__ k, ushort* __restrict__ v,
             float* __restrict__ outF, int M, int N, int K)
{
  constexpr int WN = BN / 64;       // 2 or 1
  constexpr int MI = (WN == 2) ? 4 : 2;
  constexpr int NI = 4;
  __shared__ ushort lA[128 * 64];
  __shared__ ushort lB[BN * 64];
  const int tid = threadIdx.x;
  const int w = tid >> 6, lane = tid & 63;
  const int m0 = blockIdx.x * 128, n0 = blockIdx.y * BN;
  const int g = lane >> 4, lr = lane & 15;
  const int wm = (WN == 2) ? (w >> 1) : w;
  const int wn = (WN == 2) ? (w & 1) : 0;

  const int srow = w * 8 + (lane >> 3);
  const int scol = (lane & 7) * 8;
  const ushort* ga = A + (size_t)(m0 + srow) * K + scol;
  const ushort* gb = B + (size_t)(n0 + srow) * K + scol;
  ushort* laB = lA + w * 512;
  ushort* lbB = lB + w * 512;

  v4f acc[MI][NI];
  const v4f zf = {0.0f, 0.0f, 0.0f, 0.0f};
#pragma unroll
  for (int mi = 0; mi < MI; mi++)
#pragma unroll
    for (int ni = 0; ni < NI; ni++) acc[mi][ni] = zf;

  for (int k0 = 0; k0 < K; k0 += 64) {
#pragma unroll
    for (int i = 0; i < 4; i++)
      __builtin_amdgcn_global_load_lds((const AS1 void*)(ga + (size_t)i * 32 * K + k0),
                                       (AS3 void*)(laB + i * 2048), 16, 0, 0);
#pragma unroll
    for (int i = 0; i < BN / 32; i++)
      __builtin_amdgcn_global_load_lds((const AS1 void*)(gb + (size_t)i * 32 * K + k0),
                                       (AS3 void*)(lbB + i * 2048), 16, 0, 0);
    __syncthreads();
#pragma unroll
    for (int kc = 0; kc < 2; kc++) {
      v8s af[MI], bf[NI];
#pragma unroll
      for (int mi = 0; mi < MI; mi++)
        af[mi] = *(const v8s*)(lA + (wm * (MI * 16) + mi * 16 + lr) * 64 + kc * 32 + g * 8);
#pragma unroll
      for (int ni = 0; ni < NI; ni++)
        bf[ni] = *(const v8s*)(lB + (wn * 64 + ni * 16 + lr) * 64 + kc * 32 + g * 8);
#pragma unroll
      for (int mi = 0; mi < MI; mi++)
#pragma unroll
        for (int ni = 0; ni < NI; ni++)
          acc[mi][ni] = __builtin_amdgcn_mfma_f32_16x16x32_bf16(af[mi], bf[ni], acc[mi][ni], 0, 0, 0);
    }
    __syncthreads();
  }

#pragma unroll
  for (int mi = 0; mi < MI; mi++) {
#pragma unroll
    for (int ni = 0; ni < NI; ni++) {
      v4f c = acc[mi][ni];
      const int row0 = m0 + wm * (MI * 16) + mi * 16 + g * 4;
      const int col = n0 + wn * 64 + ni * 16 + lr;
#pragma unroll
      for (int r = 0; r < 4; r++) {
        const int m = row0 + r;
        if (MODE == 0) {
          const int b = m >> 11, s = m & 2047;
          const int part = col >> 10, c2 = col & 1023;
          const int h = c2 >> 6, d = c2 & 63;
          const size_t idx = ((size_t)(b * 16 + h) * 2048 + s) * 64 + d;
          const float val = c[r];
          if (part == 0)      q[idx] = f2bf(val * 0.125f);
          else if (part == 1) k[idx] = f2bf(val);
          else                v[idx] = f2bf(val);
        } else {
          outF[(size_t)m * N + col] = c[r];
        }
      }
    }
  }
}

// ---------------- V transpose: [bh][s][d] -> [bh][d][s] ----------------
__global__ void transpose_v_kernel(const ushort* __restrict__ vh, ushort* __restrict__ vt) {
  __shared__ ushort t[64][72];
  const int bh = blockIdx.y;
  const int s0 = blockIdx.x * 64;
  const int tid = threadIdx.x;
  const int r = tid >> 2, c0 = (tid & 3) * 16;
  const ushort* src = vh + ((size_t)bh * 2048 + s0) * 64;
  v8s x0 = *(const v8s*)(src + r * 64 + c0);
  v8s x1 = *(const v8s*)(src + r * 64 + c0 + 8);
  *(v8s*)&t[r][c0] = x0;
  *(v8s*)&t[r][c0 + 8] = x1;
  __syncthreads();
  v8s y0, y1;
#pragma unroll
  for (int j = 0; j < 8; j++) ((ushort*)&y0)[j] = t[c0 + j][r];
#pragma unroll
  for (int j = 0; j < 8; j++) ((ushort*)&y1)[j] = t[c0 + 8 + j][r];
  ushort* dst = vt + ((size_t)bh * 64 + r) * 2048 + s0 + c0;
  *(v8s*)dst = y0;
  *(v8s*)(dst + 8) = y1;
}

// ---------------- flash attention v5: 4 blocks/CU ----------------
__global__ __launch_bounds__(256, 4)
void attn_kernel(const ushort* __restrict__ qh, const ushort* __restrict__ kh,
                 const ushort* __restrict__ vt, ushort* __restrict__ ao)
{
  __shared__ ushort lK0[64 * 64], lK1[64 * 64];
  __shared__ ushort lV0[64 * 64], lV1[64 * 64];
  __shared__ ushort pls[4][16][64];

  const int bh = blockIdx.x;
  const int slot = blockIdx.y;
  const int chunk = (slot < 16) ? (31 - slot) : (slot - 16);
  const int q0 = chunk * 64;
  const int NT = chunk + 1;

  const int w = threadIdx.x >> 6;
  const int lane = threadIdx.x & 63;
  const int g = lane >> 4, lr = lane & 15;
  const int lsub = lane >> 3;
  const int swz8 = ((lane & 7) ^ lsub) * 8;
  const int wrow = q0 + w * 16;

  const ushort* Qp = qh + (size_t)bh * 2048 * 64;
  const ushort* Kp = kh + (size_t)bh * 2048 * 64;
  const ushort* Vp = vt + (size_t)bh * 64 * 2048;

  v8s aq[2];
#pragma unroll
  for (int kc = 0; kc < 2; kc++)
    aq[kc] = *(const v8s*)(Qp + (size_t)(wrow + lr) * 64 + kc * 32 + g * 8);

  v4f o[4];
  float l[4];
  const v4f zf = {0.0f, 0.0f, 0.0f, 0.0f};
#pragma unroll
  for (int ni = 0; ni < 4; ni++) o[ni] = zf;
#pragma unroll
  for (int r = 0; r < 4; r++) l[r] = 0.0f;

  auto stage = [&](ushort* dK, ushort* dV, int kv0) {
#pragma unroll
    for (int i = 0; i < 2; i++) {
      __builtin_amdgcn_global_load_lds(
          (const AS1 void*)(Kp + (size_t)(kv0 + i * 32 + w * 8 + lsub) * 64 + swz8),
          (AS3 void*)(dK + (i * 32 + w * 8) * 64), 16, 0, 0);
      __builtin_amdgcn_global_load_lds(
          (const AS1 void*)(Vp + (size_t)(i * 32 + w * 8 + lsub) * 2048 + kv0 + swz8),
          (AS3 void*)(dV + (i * 32 + w * 8) * 64), 16, 0, 0);
    }
  };

  auto rdfrag = [&](const ushort* base, int ni, int kc) -> v8s {
    const int row = ni * 16 + lr;
    const int off = (((kc * 64 + g * 16) ^ ((lr & 7) << 4)) >> 1);
    return *(const v8s*)(base + row * 64 + off);
  };

  auto compute = [&](const ushort* bK, const ushort* bV, int kv0, bool diag) {
    v4f s[4];
#pragma unroll
    for (int ni = 0; ni < 4; ni++) s[ni] = zf;
#pragma unroll
    for (int kc = 0; kc < 2; kc++) {
      v8s kf[4];
#pragma unroll
      for (int ni = 0; ni < 4; ni++) kf[ni] = rdfrag(bK, ni, kc);
      __builtin_amdgcn_s_setprio(1);
#pragma unroll
      for (int ni = 0; ni < 4; ni++)
        s[ni] = __builtin_amdgcn_mfma_f32_16x16x32_bf16(aq[kc], kf[ni], s[ni], 0, 0, 0);
      __builtin_amdgcn_s_setprio(0);
    }
    if (diag) {
#pragma unroll
      for (int ni = 0; ni < 4; ni++)
#pragma unroll
        for (int r = 0; r < 4; r++) {
          const int qq = wrow + g * 4 + r;
          const int kk = kv0 + ni * 16 + lr;
          if (kk > qq) s[ni][r] = -1.0e30f;
        }
    }
#pragma unroll
    for (int ni = 0; ni < 4; ni++)
#pragma unroll
      for (int r = 0; r < 4; r++) {
        const float p = __expf(s[ni][r]);
        l[r] += p;
        pls[w][g * 4 + r][(ni * 16 + lr) ^ (g << 4)] = f2bf_trunc(p);
      }
#pragma unroll
    for (int kc = 0; kc < 2; kc++) {
      v8s ap = *(const v8s*)(&pls[w][lr][(kc * 32 + g * 8) ^ ((lr >> 2) << 4)]);
      v8s vf[4];
#pragma unroll
      for (int d = 0; d < 4; d++) vf[d] = rdfrag(bV, d, kc);
      __builtin_amdgcn_s_setprio(1);
#pragma unroll
      for (int d = 0; d < 4; d++)
        o[d] = __builtin_amdgcn_mfma_f32_16x16x32_bf16(ap, vf[d], o[d], 0, 0, 0);
      __builtin_amdgcn_s_setprio(0);
    }
  };

  stage(lK0, lV0, 0);
  asm volatile("s_waitcnt vmcnt(0)" ::: "memory");
  __builtin_amdgcn_s_barrier();

  for (int t = 0; t < NT; t++) {
    const int kv0 = t * 64;
    if ((t & 1) == 0) {
      if (t + 1 < NT) stage(lK1, lV1, kv0 + 64);
      compute(lK0, lV0, kv0, t == NT - 1);
    } else {
      if (t + 1 < NT) stage(lK0, lV0, kv0 + 64);
      compute(lK1, lV1, kv0, t == NT - 1);
    }
    asm volatile("s_waitcnt vmcnt(0)" ::: "memory");
    __builtin_amdgcn_s_barrier();
  }

#pragma unroll
  for (int r = 0; r < 4; r++) {
    l[r] += __shfl_xor(l[r], 1);
    l[r] += __shfl_xor(l[r], 2);
    l[r] += __shfl_xor(l[r], 4);
    l[r] += __shfl_xor(l[r], 8);
  }

  const int b = bh >> 4, h = bh & 15;
#pragma unroll
  for (int ni = 0; ni < 4; ni++) {
#pragma unroll
    for (int r = 0; r < 4; r++) {
      const int srow = wrow + g * 4 + r;
      ao[((size_t)(b * 2048 + srow)) * 1024 + h * 64 + ni * 16 + lr] = f2bf(o[ni][r] / l[r]);
    }
  }
}

extern "C" void kernel_launch(void* const* d_in, const int* in_sizes, int n_in,
                              void* d_out, int out_size, void* d_ws, size_t ws_size,
                              hipStream_t stream)
{
  const float* x     = (const float*)d_in[0];
  // d_in[1] = attention_mask (causal by construction; unused)
  const float* w_qkv = (const float*)d_in[2];
  const float* w_out = (const float*)d_in[3];
  float* out = (float*)d_out;

  char* ws = (char*)d_ws;
  ushort* xb  = (ushort*)(ws);                              // 8 MB (reused as ao)
  ushort* wqb = (ushort*)(ws + (size_t)8  * 1024 * 1024);   // 6 MB
  ushort* wob = (ushort*)(ws + (size_t)14 * 1024 * 1024);   // 2 MB
  ushort* qh  = (ushort*)(ws + (size_t)16 * 1024 * 1024);   // 8 MB
  ushort* kh  = (ushort*)(ws + (size_t)24 * 1024 * 1024);   // 8 MB
  ushort* vh  = (ushort*)(ws + (size_t)32 * 1024 * 1024);   // 8 MB
  ushort* vt  = (ushort*)(ws + (size_t)40 * 1024 * 1024);   // 8 MB
  ushort* ao  = xb;  // xb dead after gemm_qkv

  cast_bf16_kernel<<<4096, 256, 0, stream>>>(x, xb, 1048576);
  cast_bf16_kernel<<<3072, 256, 0, stream>>>(w_qkv, wqb, 786432);
  cast_bf16_kernel<<<1024, 256, 0, stream>>>(w_out, wob, 262144);
  gemm_qkv_8ph<<<dim3(16, 12), 512, 0, stream>>>(xb, wqb, qh, kh, vh);
  transpose_v_kernel<<<dim3(32, 32), 256, 0, stream>>>(vh, vt);
  attn_kernel<<<dim3(32, 32), 256, 0, stream>>>(qh, kh, vt, ao);
  gemm_bt<1, 64><<<dim3(32, 16), 256, 0, stream>>>(ao, wob, nullptr, nullptr, nullptr, out, 4096, 1024, 1024);
}

// Round 7
// 109.228 us; speedup vs baseline: 1.0859x; 1.0859x over previous
//
#include <hip/hip_runtime.h>

typedef short v8s __attribute__((ext_vector_type(8)));
typedef float v4f __attribute__((ext_vector_type(4)));

#define AS1 __attribute__((address_space(1)))
#define AS3 __attribute__((address_space(3)))

__device__ __forceinline__ ushort f2bf(float f) {
  union { float f; unsigned u; } v; v.f = f;
  unsigned u = v.u;
  unsigned r = (u + 0x7FFFu + ((u >> 16) & 1u)) >> 16;
  return (ushort)r;
}

__device__ __forceinline__ ushort f2bf_trunc(float f) {
  union { float f; unsigned u; } v; v.f = f;
  return (ushort)(v.u >> 16);
}

// ---------------- fused cast fp32 -> bf16 (x, w_qkv, w_out in one launch) ---
__global__ void cast3_kernel(const float* __restrict__ a, int na4,
                             const float* __restrict__ b, int nb4,
                             const float* __restrict__ c, int nc4,
                             ushort* __restrict__ da, ushort* __restrict__ db,
                             ushort* __restrict__ dc) {
  int i = blockIdx.x * blockDim.x + threadIdx.x;
  const float* s; ushort* d; int off;
  if (i < na4) { s = a; d = da; off = i; }
  else if (i < na4 + nb4) { s = b; d = db; off = i - na4; }
  else if (i < na4 + nb4 + nc4) { s = c; d = dc; off = i - na4 - nb4; }
  else return;
  float4 f = ((const float4*)s)[off];
  ushort4 o;
  o.x = f2bf(f.x); o.y = f2bf(f.y); o.z = f2bf(f.z); o.w = f2bf(f.w);
  ((ushort4*)d)[off] = o;
}

// ---------------- GEMM: C[M][N] = A[M][K] * B[N][K]^T (bf16 in, fp32 acc) ----
// Double-buffered LDS (stage t+1 before compute t; one vmcnt(0)+barrier per
// K-tile) + T2 swizzle both-sides (pre-swizzled glds source col
// ((l&7)^(l>>3))*8, ds_read col XOR (lr&7)<<3 -> 0 conflicts, proven r6).
// BM=128; BN 128 (2 blocks/CU) or 64 (3 blocks/CU).
template<int MODE, int BN>
__global__ __launch_bounds__(256, (BN == 128) ? 2 : 3)
void gemm_bt(const ushort* __restrict__ A, const ushort* __restrict__ B,
             ushort* __restrict__ q, ushort* __restrict__ k, ushort* __restrict__ v,
             float* __restrict__ outF, int M, int N, int K)
{
  constexpr int WN = BN / 64;       // 2 or 1
  constexpr int MI = (WN == 2) ? 4 : 2;
  constexpr int NI = 4;
  __shared__ ushort lA[2][128 * 64];
  __shared__ ushort lB[2][BN * 64];
  const int tid = threadIdx.x;
  const int w = tid >> 6, lane = tid & 63;
  const int m0 = blockIdx.x * 128, n0 = blockIdx.y * BN;
  const int g = lane >> 4, lr = lane & 15;
  const int wm = (WN == 2) ? (w >> 1) : w;
  const int wn = (WN == 2) ? (w & 1) : 0;

  const int r8 = lane >> 3;
  const int swz8 = ((lane & 7) ^ r8) * 8;   // pre-swizzled source col (ushort)
  const ushort* ga = A + (size_t)(m0 + w * 8 + r8) * K + swz8;
  const ushort* gb = B + (size_t)(n0 + w * 8 + r8) * K + swz8;
  const int xr = (lr & 7) << 3;             // read-side XOR (ushort units)

  v4f acc[MI][NI];
  const v4f zf = {0.0f, 0.0f, 0.0f, 0.0f};
#pragma unroll
  for (int mi = 0; mi < MI; mi++)
#pragma unroll
    for (int ni = 0; ni < NI; ni++) acc[mi][ni] = zf;

  auto stage = [&](int buf, int k0) {
#pragma unroll
    for (int i = 0; i < 4; i++)
      __builtin_amdgcn_global_load_lds((const AS1 void*)(ga + (size_t)(i * 32) * K + k0),
                                       (AS3 void*)(&lA[buf][(i * 32 + w * 8) * 64]), 16, 0, 0);
#pragma unroll
    for (int i = 0; i < BN / 32; i++)
      __builtin_amdgcn_global_load_lds((const AS1 void*)(gb + (size_t)(i * 32) * K + k0),
                                       (AS3 void*)(&lB[buf][(i * 32 + w * 8) * 64]), 16, 0, 0);
  };

  stage(0, 0);
  asm volatile("s_waitcnt vmcnt(0)" ::: "memory");
  asm volatile("s_barrier" ::: "memory");

  const int NTk = K >> 6;
  for (int t = 0; t < NTk; t++) {
    const int c = t & 1;
    if (t + 1 < NTk) stage(c ^ 1, (t + 1) * 64);
#pragma unroll
    for (int kc = 0; kc < 2; kc++) {
      v8s af[MI], bf[NI];
#pragma unroll
      for (int mi = 0; mi < MI; mi++)
        af[mi] = *(const v8s*)(&lA[c][(wm * (MI * 16) + mi * 16 + lr) * 64 + ((kc * 32 + g * 8) ^ xr)]);
#pragma unroll
      for (int ni = 0; ni < NI; ni++)
        bf[ni] = *(const v8s*)(&lB[c][(wn * 64 + ni * 16 + lr) * 64 + ((kc * 32 + g * 8) ^ xr)]);
      __builtin_amdgcn_s_setprio(1);
#pragma unroll
      for (int mi = 0; mi < MI; mi++)
#pragma unroll
        for (int ni = 0; ni < NI; ni++)
          acc[mi][ni] = __builtin_amdgcn_mfma_f32_16x16x32_bf16(af[mi], bf[ni], acc[mi][ni], 0, 0, 0);
      __builtin_amdgcn_s_setprio(0);
    }
    asm volatile("s_waitcnt vmcnt(0)" ::: "memory");
    asm volatile("s_barrier" ::: "memory");
  }

#pragma unroll
  for (int mi = 0; mi < MI; mi++) {
#pragma unroll
    for (int ni = 0; ni < NI; ni++) {
      v4f c = acc[mi][ni];
      const int row0 = m0 + wm * (MI * 16) + mi * 16 + g * 4;
      const int col = n0 + wn * 64 + ni * 16 + lr;
#pragma unroll
      for (int r = 0; r < 4; r++) {
        const int m = row0 + r;
        if (MODE == 0) {
          const int b = m >> 11, s = m & 2047;
          const int part = col >> 10, c2 = col & 1023;
          const int h = c2 >> 6, d = c2 & 63;
          const size_t idx = ((size_t)(b * 16 + h) * 2048 + s) * 64 + d;
          const float val = c[r];
          if (part == 0)      q[idx] = f2bf(val * 0.125f);
          else if (part == 1) k[idx] = f2bf(val);
          else                v[idx] = f2bf(val);
        } else {
          outF[(size_t)m * N + col] = c[r];
        }
      }
    }
  }
}

// ---------------- V transpose: [bh][s][d] -> [bh][d][s] ----------------
__global__ void transpose_v_kernel(const ushort* __restrict__ vh, ushort* __restrict__ vt) {
  __shared__ ushort t[64][72];
  const int bh = blockIdx.y;
  const int s0 = blockIdx.x * 64;
  const int tid = threadIdx.x;
  const int r = tid >> 2, c0 = (tid & 3) * 16;
  const ushort* src = vh + ((size_t)bh * 2048 + s0) * 64;
  v8s x0 = *(const v8s*)(src + r * 64 + c0);
  v8s x1 = *(const v8s*)(src + r * 64 + c0 + 8);
  *(v8s*)&t[r][c0] = x0;
  *(v8s*)&t[r][c0 + 8] = x1;
  __syncthreads();
  v8s y0, y1;
#pragma unroll
  for (int j = 0; j < 8; j++) ((ushort*)&y0)[j] = t[c0 + j][r];
#pragma unroll
  for (int j = 0; j < 8; j++) ((ushort*)&y1)[j] = t[c0 + 8 + j][r];
  ushort* dst = vt + ((size_t)bh * 64 + r) * 2048 + s0 + c0;
  *(v8s*)dst = y0;
  *(v8s*)(dst + 8) = y1;
}

// ---------------- flash attention v5: 4 blocks/CU (unchanged) ----------------
__global__ __launch_bounds__(256, 4)
void attn_kernel(const ushort* __restrict__ qh, const ushort* __restrict__ kh,
                 const ushort* __restrict__ vt, ushort* __restrict__ ao)
{
  __shared__ ushort lK0[64 * 64], lK1[64 * 64];
  __shared__ ushort lV0[64 * 64], lV1[64 * 64];
  __shared__ ushort pls[4][16][64];

  const int bh = blockIdx.x;
  const int slot = blockIdx.y;
  const int chunk = (slot < 16) ? (31 - slot) : (slot - 16);
  const int q0 = chunk * 64;
  const int NT = chunk + 1;

  const int w = threadIdx.x >> 6;
  const int lane = threadIdx.x & 63;
  const int g = lane >> 4, lr = lane & 15;
  const int lsub = lane >> 3;
  const int swz8 = ((lane & 7) ^ lsub) * 8;
  const int wrow = q0 + w * 16;

  const ushort* Qp = qh + (size_t)bh * 2048 * 64;
  const ushort* Kp = kh + (size_t)bh * 2048 * 64;
  const ushort* Vp = vt + (size_t)bh * 64 * 2048;

  v8s aq[2];
#pragma unroll
  for (int kc = 0; kc < 2; kc++)
    aq[kc] = *(const v8s*)(Qp + (size_t)(wrow + lr) * 64 + kc * 32 + g * 8);

  v4f o[4];
  float l[4];
  const v4f zf = {0.0f, 0.0f, 0.0f, 0.0f};
#pragma unroll
  for (int ni = 0; ni < 4; ni++) o[ni] = zf;
#pragma unroll
  for (int r = 0; r < 4; r++) l[r] = 0.0f;

  auto stage = [&](ushort* dK, ushort* dV, int kv0) {
#pragma unroll
    for (int i = 0; i < 2; i++) {
      __builtin_amdgcn_global_load_lds(
          (const AS1 void*)(Kp + (size_t)(kv0 + i * 32 + w * 8 + lsub) * 64 + swz8),
          (AS3 void*)(dK + (i * 32 + w * 8) * 64), 16, 0, 0);
      __builtin_amdgcn_global_load_lds(
          (const AS1 void*)(Vp + (size_t)(i * 32 + w * 8 + lsub) * 2048 + kv0 + swz8),
          (AS3 void*)(dV + (i * 32 + w * 8) * 64), 16, 0, 0);
    }
  };

  auto rdfrag = [&](const ushort* base, int ni, int kc) -> v8s {
    const int row = ni * 16 + lr;
    const int off = (((kc * 64 + g * 16) ^ ((lr & 7) << 4)) >> 1);
    return *(const v8s*)(base + row * 64 + off);
  };

  auto compute = [&](const ushort* bK, const ushort* bV, int kv0, bool diag) {
    v4f s[4];
#pragma unroll
    for (int ni = 0; ni < 4; ni++) s[ni] = zf;
#pragma unroll
    for (int kc = 0; kc < 2; kc++) {
      v8s kf[4];
#pragma unroll
      for (int ni = 0; ni < 4; ni++) kf[ni] = rdfrag(bK, ni, kc);
      __builtin_amdgcn_s_setprio(1);
#pragma unroll
      for (int ni = 0; ni < 4; ni++)
        s[ni] = __builtin_amdgcn_mfma_f32_16x16x32_bf16(aq[kc], kf[ni], s[ni], 0, 0, 0);
      __builtin_amdgcn_s_setprio(0);
    }
    if (diag) {
#pragma unroll
      for (int ni = 0; ni < 4; ni++)
#pragma unroll
        for (int r = 0; r < 4; r++) {
          const int qq = wrow + g * 4 + r;
          const int kk = kv0 + ni * 16 + lr;
          if (kk > qq) s[ni][r] = -1.0e30f;
        }
    }
#pragma unroll
    for (int ni = 0; ni < 4; ni++)
#pragma unroll
      for (int r = 0; r < 4; r++) {
        const float p = __expf(s[ni][r]);
        l[r] += p;
        pls[w][g * 4 + r][(ni * 16 + lr) ^ (g << 4)] = f2bf_trunc(p);
      }
#pragma unroll
    for (int kc = 0; kc < 2; kc++) {
      v8s ap = *(const v8s*)(&pls[w][lr][(kc * 32 + g * 8) ^ ((lr >> 2) << 4)]);
      v8s vf[4];
#pragma unroll
      for (int d = 0; d < 4; d++) vf[d] = rdfrag(bV, d, kc);
      __builtin_amdgcn_s_setprio(1);
#pragma unroll
      for (int d = 0; d < 4; d++)
        o[d] = __builtin_amdgcn_mfma_f32_16x16x32_bf16(ap, vf[d], o[d], 0, 0, 0);
      __builtin_amdgcn_s_setprio(0);
    }
  };

  stage(lK0, lV0, 0);
  asm volatile("s_waitcnt vmcnt(0)" ::: "memory");
  __builtin_amdgcn_s_barrier();

  for (int t = 0; t < NT; t++) {
    const int kv0 = t * 64;
    if ((t & 1) == 0) {
      if (t + 1 < NT) stage(lK1, lV1, kv0 + 64);
      compute(lK0, lV0, kv0, t == NT - 1);
    } else {
      if (t + 1 < NT) stage(lK0, lV0, kv0 + 64);
      compute(lK1, lV1, kv0, t == NT - 1);
    }
    asm volatile("s_waitcnt vmcnt(0)" ::: "memory");
    __builtin_amdgcn_s_barrier();
  }

#pragma unroll
  for (int r = 0; r < 4; r++) {
    l[r] += __shfl_xor(l[r], 1);
    l[r] += __shfl_xor(l[r], 2);
    l[r] += __shfl_xor(l[r], 4);
    l[r] += __shfl_xor(l[r], 8);
  }

  const int b = bh >> 4, h = bh & 15;
#pragma unroll
  for (int ni = 0; ni < 4; ni++) {
#pragma unroll
    for (int r = 0; r < 4; r++) {
      const int srow = wrow + g * 4 + r;
      ao[((size_t)(b * 2048 + srow)) * 1024 + h * 64 + ni * 16 + lr] = f2bf(o[ni][r] / l[r]);
    }
  }
}

extern "C" void kernel_launch(void* const* d_in, const int* in_sizes, int n_in,
                              void* d_out, int out_size, void* d_ws, size_t ws_size,
                              hipStream_t stream)
{
  const float* x     = (const float*)d_in[0];
  // d_in[1] = attention_mask (causal by construction; unused)
  const float* w_qkv = (const float*)d_in[2];
  const float* w_out = (const float*)d_in[3];
  float* out = (float*)d_out;

  char* ws = (char*)d_ws;
  ushort* xb  = (ushort*)(ws);                              // 8 MB (reused as ao)
  ushort* wqb = (ushort*)(ws + (size_t)8  * 1024 * 1024);   // 6 MB
  ushort* wob = (ushort*)(ws + (size_t)14 * 1024 * 1024);   // 2 MB
  ushort* qh  = (ushort*)(ws + (size_t)16 * 1024 * 1024);   // 8 MB
  ushort* kh  = (ushort*)(ws + (size_t)24 * 1024 * 1024);   // 8 MB
  ushort* vh  = (ushort*)(ws + (size_t)32 * 1024 * 1024);   // 8 MB
  ushort* vt  = (ushort*)(ws + (size_t)40 * 1024 * 1024);   // 8 MB
  ushort* ao  = xb;  // xb dead after gemm_qkv

  cast3_kernel<<<8192, 256, 0, stream>>>(x, 1048576, w_qkv, 786432, w_out, 262144,
                                         xb, wqb, wob);
  gemm_bt<0, 128><<<dim3(32, 24), 256, 0, stream>>>(xb, wqb, qh, kh, vh, nullptr, 4096, 3072, 1024);
  transpose_v_kernel<<<dim3(32, 32), 256, 0, stream>>>(vh, vt);
  attn_kernel<<<dim3(32, 32), 256, 0, stream>>>(qh, kh, vt, ao);
  gemm_bt<1, 64><<<dim3(32, 16), 256, 0, stream>>>(ao, wob, nullptr, nullptr, nullptr, out, 4096, 1024, 1024);
}

// Round 8
// 92.368 us; speedup vs baseline: 1.2841x; 1.1825x over previous
//
#include <hip/hip_runtime.h>

typedef short v8s __attribute__((ext_vector_type(8)));
typedef float v4f __attribute__((ext_vector_type(4)));

#define AS1 __attribute__((address_space(1)))
#define AS3 __attribute__((address_space(3)))

__device__ __forceinline__ ushort f2bf(float f) {
  union { float f; unsigned u; } v; v.f = f;
  unsigned u = v.u;
  unsigned r = (u + 0x7FFFu + ((u >> 16) & 1u)) >> 16;
  return (ushort)r;
}

__device__ __forceinline__ ushort f2bf_trunc(float f) {
  union { float f; unsigned u; } v; v.f = f;
  return (ushort)(v.u >> 16);
}

// ---------------- fused cast fp32 -> bf16 ----------------
__global__ void cast3_kernel(const float* __restrict__ a, int na4,
                             const float* __restrict__ b, int nb4,
                             const float* __restrict__ c, int nc4,
                             ushort* __restrict__ da, ushort* __restrict__ db,
                             ushort* __restrict__ dc) {
  int i = blockIdx.x * blockDim.x + threadIdx.x;
  const float* s; ushort* d; int off;
  if (i < na4) { s = a; d = da; off = i; }
  else if (i < na4 + nb4) { s = b; d = db; off = i - na4; }
  else if (i < na4 + nb4 + nc4) { s = c; d = dc; off = i - na4 - nb4; }
  else return;
  float4 f = ((const float4*)s)[off];
  ushort4 o;
  o.x = f2bf(f.x); o.y = f2bf(f.y); o.z = f2bf(f.z); o.w = f2bf(f.w);
  ((ushort4*)d)[off] = o;
}

// ---------------- GEMM v2: single-buffer, swizzled, stage-under-MFMA -------
// C[M][N] = A[M][K] * B[N][K]^T (bf16 in, fp32 acc).
// Schedule per K-tile: {ds_read 16 frags; lgkmcnt(0)+bar; stage(t+1) into SAME
// buffer (reads drained); sched_barrier; 32 MFMA (reg-only, overlaps stage);
// vmcnt(0)+bar}. Single buffer keeps LDS at 32/24 KB -> 3 blocks/CU.
// Swizzle both-sides (rule #21): glds source col ((l&7)^(l>>3))*8, ds_read
// col XOR (lr&7)<<3 -> 0 bank conflicts (verified r6/r7).
// MODE 0: epilogue scatters q (x0.125), k into [bh][s][d] and V DIRECTLY
// TRANSPOSED into vt [bh][d][s] (packed 8B stores). MODE 1: fp32 out.
template<int MODE, int BN>
__global__ __launch_bounds__(256, 3)
void gemm_bt(const ushort* __restrict__ A, const ushort* __restrict__ B,
             ushort* __restrict__ q, ushort* __restrict__ k, ushort* __restrict__ vtp,
             float* __restrict__ outF, int M, int N, int K)
{
  constexpr int WN = BN / 64;       // 2 or 1
  constexpr int MI = (WN == 2) ? 4 : 2;
  constexpr int NI = 4;
  __shared__ ushort lA[128 * 64];
  __shared__ ushort lB[BN * 64];
  const int tid = threadIdx.x;
  const int w = tid >> 6, lane = tid & 63;
  const int m0 = blockIdx.x * 128, n0 = blockIdx.y * BN;
  const int g = lane >> 4, lr = lane & 15;
  const int wm = (WN == 2) ? (w >> 1) : w;
  const int wn = (WN == 2) ? (w & 1) : 0;

  const int r8 = lane >> 3;
  const int swz8 = ((lane & 7) ^ r8) * 8;   // pre-swizzled source col (ushort)
  const ushort* ga = A + (size_t)(m0 + w * 8 + r8) * K + swz8;
  const ushort* gb = B + (size_t)(n0 + w * 8 + r8) * K + swz8;
  const int xr = (lr & 7) << 3;             // read-side XOR (ushort units)

  v4f acc[MI][NI];
  const v4f zf = {0.0f, 0.0f, 0.0f, 0.0f};
#pragma unroll
  for (int mi = 0; mi < MI; mi++)
#pragma unroll
    for (int ni = 0; ni < NI; ni++) acc[mi][ni] = zf;

  auto stage = [&](int k0) {
#pragma unroll
    for (int i = 0; i < 4; i++)
      __builtin_amdgcn_global_load_lds((const AS1 void*)(ga + (size_t)(i * 32) * K + k0),
                                       (AS3 void*)(&lA[(i * 32 + w * 8) * 64]), 16, 0, 0);
#pragma unroll
    for (int i = 0; i < BN / 32; i++)
      __builtin_amdgcn_global_load_lds((const AS1 void*)(gb + (size_t)(i * 32) * K + k0),
                                       (AS3 void*)(&lB[(i * 32 + w * 8) * 64]), 16, 0, 0);
  };

  stage(0);
  asm volatile("s_waitcnt vmcnt(0)" ::: "memory");
  asm volatile("s_barrier" ::: "memory");

  const int NTk = K >> 6;
  for (int t = 0; t < NTk; t++) {
    v8s af[MI][2], bf[NI][2];
#pragma unroll
    for (int mi = 0; mi < MI; mi++)
#pragma unroll
      for (int kc = 0; kc < 2; kc++)
        af[mi][kc] = *(const v8s*)(&lA[(wm * (MI * 16) + mi * 16 + lr) * 64 + ((kc * 32 + g * 8) ^ xr)]);
#pragma unroll
    for (int ni = 0; ni < NI; ni++)
#pragma unroll
      for (int kc = 0; kc < 2; kc++)
        bf[ni][kc] = *(const v8s*)(&lB[(wn * 64 + ni * 16 + lr) * 64 + ((kc * 32 + g * 8) ^ xr)]);
    // all reads drained before anyone overwrites the buffer
    asm volatile("s_waitcnt lgkmcnt(0)" ::: "memory");
    asm volatile("s_barrier" ::: "memory");
    if (t + 1 < NTk) stage((t + 1) * 64);
    __builtin_amdgcn_sched_barrier(0);
    __builtin_amdgcn_s_setprio(1);
#pragma unroll
    for (int kc = 0; kc < 2; kc++)
#pragma unroll
      for (int mi = 0; mi < MI; mi++)
#pragma unroll
        for (int ni = 0; ni < NI; ni++)
          acc[mi][ni] = __builtin_amdgcn_mfma_f32_16x16x32_bf16(af[mi][kc], bf[ni][kc], acc[mi][ni], 0, 0, 0);
    __builtin_amdgcn_s_setprio(0);
    asm volatile("s_waitcnt vmcnt(0)" ::: "memory");
    asm volatile("s_barrier" ::: "memory");
  }

#pragma unroll
  for (int mi = 0; mi < MI; mi++) {
#pragma unroll
    for (int ni = 0; ni < NI; ni++) {
      v4f c = acc[mi][ni];
      const int row0 = m0 + wm * (MI * 16) + mi * 16 + g * 4;
      const int col = n0 + wn * 64 + ni * 16 + lr;
      if (MODE == 0) {
        const int b = row0 >> 11, s0r = row0 & 2047;
        const int part = col >> 10, c2 = col & 1023;
        const int h = c2 >> 6, d = c2 & 63;
        if (part == 2) {
          // V: write transposed [bh][d][s], 4 s-values packed (8B store)
          ushort4 pk;
          pk.x = f2bf(c[0]); pk.y = f2bf(c[1]); pk.z = f2bf(c[2]); pk.w = f2bf(c[3]);
          *(ushort4*)(vtp + ((size_t)(b * 16 + h) * 64 + d) * 2048 + s0r) = pk;
        } else {
          const size_t idx = ((size_t)(b * 16 + h) * 2048 + s0r) * 64 + d;
#pragma unroll
          for (int r = 0; r < 4; r++) {
            const float val = c[r];
            if (part == 0) q[idx + (size_t)r * 64] = f2bf(val * 0.125f);
            else           k[idx + (size_t)r * 64] = f2bf(val);
          }
        }
      } else {
#pragma unroll
        for (int r = 0; r < 4; r++)
          outF[(size_t)(row0 + r) * N + col] = c[r];
      }
    }
  }
}

// ---------------- flash attention v5: 4 blocks/CU (unchanged) ----------------
__global__ __launch_bounds__(256, 4)
void attn_kernel(const ushort* __restrict__ qh, const ushort* __restrict__ kh,
                 const ushort* __restrict__ vt, ushort* __restrict__ ao)
{
  __shared__ ushort lK0[64 * 64], lK1[64 * 64];
  __shared__ ushort lV0[64 * 64], lV1[64 * 64];
  __shared__ ushort pls[4][16][64];

  const int bh = blockIdx.x;
  const int slot = blockIdx.y;
  const int chunk = (slot < 16) ? (31 - slot) : (slot - 16);
  const int q0 = chunk * 64;
  const int NT = chunk + 1;

  const int w = threadIdx.x >> 6;
  const int lane = threadIdx.x & 63;
  const int g = lane >> 4, lr = lane & 15;
  const int lsub = lane >> 3;
  const int swz8 = ((lane & 7) ^ lsub) * 8;
  const int wrow = q0 + w * 16;

  const ushort* Qp = qh + (size_t)bh * 2048 * 64;
  const ushort* Kp = kh + (size_t)bh * 2048 * 64;
  const ushort* Vp = vt + (size_t)bh * 64 * 2048;

  v8s aq[2];
#pragma unroll
  for (int kc = 0; kc < 2; kc++)
    aq[kc] = *(const v8s*)(Qp + (size_t)(wrow + lr) * 64 + kc * 32 + g * 8);

  v4f o[4];
  float l[4];
  const v4f zf = {0.0f, 0.0f, 0.0f, 0.0f};
#pragma unroll
  for (int ni = 0; ni < 4; ni++) o[ni] = zf;
#pragma unroll
  for (int r = 0; r < 4; r++) l[r] = 0.0f;

  auto stage = [&](ushort* dK, ushort* dV, int kv0) {
#pragma unroll
    for (int i = 0; i < 2; i++) {
      __builtin_amdgcn_global_load_lds(
          (const AS1 void*)(Kp + (size_t)(kv0 + i * 32 + w * 8 + lsub) * 64 + swz8),
          (AS3 void*)(dK + (i * 32 + w * 8) * 64), 16, 0, 0);
      __builtin_amdgcn_global_load_lds(
          (const AS1 void*)(Vp + (size_t)(i * 32 + w * 8 + lsub) * 2048 + kv0 + swz8),
          (AS3 void*)(dV + (i * 32 + w * 8) * 64), 16, 0, 0);
    }
  };

  auto rdfrag = [&](const ushort* base, int ni, int kc) -> v8s {
    const int row = ni * 16 + lr;
    const int off = (((kc * 64 + g * 16) ^ ((lr & 7) << 4)) >> 1);
    return *(const v8s*)(base + row * 64 + off);
  };

  auto compute = [&](const ushort* bK, const ushort* bV, int kv0, bool diag) {
    v4f s[4];
#pragma unroll
    for (int ni = 0; ni < 4; ni++) s[ni] = zf;
#pragma unroll
    for (int kc = 0; kc < 2; kc++) {
      v8s kf[4];
#pragma unroll
      for (int ni = 0; ni < 4; ni++) kf[ni] = rdfrag(bK, ni, kc);
      __builtin_amdgcn_s_setprio(1);
#pragma unroll
      for (int ni = 0; ni < 4; ni++)
        s[ni] = __builtin_amdgcn_mfma_f32_16x16x32_bf16(aq[kc], kf[ni], s[ni], 0, 0, 0);
      __builtin_amdgcn_s_setprio(0);
    }
    if (diag) {
#pragma unroll
      for (int ni = 0; ni < 4; ni++)
#pragma unroll
        for (int r = 0; r < 4; r++) {
          const int qq = wrow + g * 4 + r;
          const int kk = kv0 + ni * 16 + lr;
          if (kk > qq) s[ni][r] = -1.0e30f;
        }
    }
#pragma unroll
    for (int ni = 0; ni < 4; ni++)
#pragma unroll
      for (int r = 0; r < 4; r++) {
        const float p = __expf(s[ni][r]);
        l[r] += p;
        pls[w][g * 4 + r][(ni * 16 + lr) ^ (g << 4)] = f2bf_trunc(p);
      }
#pragma unroll
    for (int kc = 0; kc < 2; kc++) {
      v8s ap = *(const v8s*)(&pls[w][lr][(kc * 32 + g * 8) ^ ((lr >> 2) << 4)]);
      v8s vf[4];
#pragma unroll
      for (int d = 0; d < 4; d++) vf[d] = rdfrag(bV, d, kc);
      __builtin_amdgcn_s_setprio(1);
#pragma unroll
      for (int d = 0; d < 4; d++)
        o[d] = __builtin_amdgcn_mfma_f32_16x16x32_bf16(ap, vf[d], o[d], 0, 0, 0);
      __builtin_amdgcn_s_setprio(0);
    }
  };

  stage(lK0, lV0, 0);
  asm volatile("s_waitcnt vmcnt(0)" ::: "memory");
  __builtin_amdgcn_s_barrier();

  for (int t = 0; t < NT; t++) {
    const int kv0 = t * 64;
    if ((t & 1) == 0) {
      if (t + 1 < NT) stage(lK1, lV1, kv0 + 64);
      compute(lK0, lV0, kv0, t == NT - 1);
    } else {
      if (t + 1 < NT) stage(lK0, lV0, kv0 + 64);
      compute(lK1, lV1, kv0, t == NT - 1);
    }
    asm volatile("s_waitcnt vmcnt(0)" ::: "memory");
    __builtin_amdgcn_s_barrier();
  }

#pragma unroll
  for (int r = 0; r < 4; r++) {
    l[r] += __shfl_xor(l[r], 1);
    l[r] += __shfl_xor(l[r], 2);
    l[r] += __shfl_xor(l[r], 4);
    l[r] += __shfl_xor(l[r], 8);
  }

  const int b = bh >> 4, h = bh & 15;
#pragma unroll
  for (int ni = 0; ni < 4; ni++) {
#pragma unroll
    for (int r = 0; r < 4; r++) {
      const int srow = wrow + g * 4 + r;
      ao[((size_t)(b * 2048 + srow)) * 1024 + h * 64 + ni * 16 + lr] = f2bf(o[ni][r] / l[r]);
    }
  }
}

extern "C" void kernel_launch(void* const* d_in, const int* in_sizes, int n_in,
                              void* d_out, int out_size, void* d_ws, size_t ws_size,
                              hipStream_t stream)
{
  const float* x     = (const float*)d_in[0];
  // d_in[1] = attention_mask (causal by construction; unused)
  const float* w_qkv = (const float*)d_in[2];
  const float* w_out = (const float*)d_in[3];
  float* out = (float*)d_out;

  char* ws = (char*)d_ws;
  ushort* xb  = (ushort*)(ws);                              // 8 MB (reused as ao)
  ushort* wqb = (ushort*)(ws + (size_t)8  * 1024 * 1024);   // 6 MB
  ushort* wob = (ushort*)(ws + (size_t)14 * 1024 * 1024);   // 2 MB
  ushort* qh  = (ushort*)(ws + (size_t)16 * 1024 * 1024);   // 8 MB
  ushort* kh  = (ushort*)(ws + (size_t)24 * 1024 * 1024);   // 8 MB
  ushort* vt  = (ushort*)(ws + (size_t)32 * 1024 * 1024);   // 8 MB
  ushort* ao  = xb;  // xb dead after gemm_qkv

  cast3_kernel<<<8192, 256, 0, stream>>>(x, 1048576, w_qkv, 786432, w_out, 262144,
                                         xb, wqb, wob);
  gemm_bt<0, 128><<<dim3(32, 24), 256, 0, stream>>>(xb, wqb, qh, kh, vt, nullptr, 4096, 3072, 1024);
  attn_kernel<<<dim3(32, 32), 256, 0, stream>>>(qh, kh, vt, ao);
  gemm_bt<1, 64><<<dim3(32, 16), 256, 0, stream>>>(ao, wob, nullptr, nullptr, nullptr, out, 4096, 1024, 1024);
}